// Round 21
// baseline (386.980 us; speedup 1.0000x reference)
//
#include <hip/hip_runtime.h>
#include <math.h>

// ---------------------------------------------------------------------------
// GAT 3-layer net. R33 = R31/R32 resubmitted verbatim (neither ran: GPU
// acquisition timeouts x2). One change vs R30 (last measured, 367.6 us):
//   k_agg restructured: block-per-node (256 thr, LDS staging, 3+ barriers)
//   -> WAVE-per-node (4 nodes/block, grid N/4), ZERO barriers, no LDS.
//   Each wave: 4-head online softmax in registers (k_layer3 pattern) +
//   wave shuffle-reduce; lane owns cols j*256+lane*4 for j=0..3 (coalesced);
//   gather = 2-deep prefetch x 4x4B loads/edge; alphas recomputed per lane
//   from one float4 als load (VALU-cheap, replaces LDS + 2 barriers/chunk).
//   Rationale: avg deg ~16 -> per-node work tiny; R30 showed agg chains
//   weren't the cost, but block-wide barrier/LDS overhead remains the one
//   identifiable structural waste in the invisible ~240us non-GEMM lump.
// Unchanged: BK=32 3-buffer/1-barrier counted-vmcnt GEMM, 128x128 tile,
// XOR swizzle, XCD grid swizzle, fp8 H, fused attn dots L1/L2, GEMM3
// split-K x4, k_layer3 parallel-alpha staging (R30).
// ---------------------------------------------------------------------------

__device__ __forceinline__ float leaky(float x){ return x > 0.f ? x : 0.2f * x; }

__device__ __forceinline__ float bf2f(unsigned short u){
  union { unsigned int i; float f; } v; v.i = ((unsigned int)u) << 16; return v.f;
}
__device__ __forceinline__ unsigned short f2bf(float f){
  union { float f; unsigned int i; } v; v.f = f;
  unsigned int r = v.i + 0x7FFF + ((v.i >> 16) & 1);   // RNE
  return (unsigned short)(r >> 16);
}
__device__ __forceinline__ float4 loadbf4(const unsigned short* p){
  ushort4 u = *(const ushort4*)p;
  return make_float4(bf2f(u.x), bf2f(u.y), bf2f(u.z), bf2f(u.w));
}

// ---- fp8 e4m3 helpers (HW cvt; self-consistent round-trip) ----
typedef __attribute__((ext_vector_type(2))) float f2v;
__device__ __forceinline__ unsigned char f2fp8(float x){
  int v = __builtin_amdgcn_cvt_pk_fp8_f32(x, x, 0, false);
  return (unsigned char)(v & 0xff);
}
__device__ __forceinline__ float4 fp8x4(unsigned int u){
  f2v a = __builtin_amdgcn_cvt_pk_f32_fp8((int)u, false);
  f2v b = __builtin_amdgcn_cvt_pk_f32_fp8((int)u, true);
  return make_float4(a.x, a.y, b.x, b.y);
}

// ---------------- mega prep kernel ----------------
__device__ __forceinline__ void tr_tile(const float* __restrict__ W,
                                        unsigned short* __restrict__ Wt,
                                        int K, int N, int rowOff, int lb,
                                        unsigned short tile[32][33]){
  int gx = K >> 5;
  int bk = (lb % gx) << 5;
  int bn = (lb / gx) << 5;
  int tx = threadIdx.x & 31;
  int ty = threadIdx.x >> 5;
#pragma unroll
  for (int r = 0; r < 32; r += 8)
    tile[ty + r][tx] = f2bf(W[(size_t)(bk + ty + r) * N + bn + tx]);
  __syncthreads();
#pragma unroll
  for (int r = 0; r < 32; r += 8)
    Wt[(size_t)(rowOff + bn + ty + r) * K + bk + tx] = tile[tx][ty + r];
}

__global__ __launch_bounds__(256) void k_prep(
    const float* __restrict__ W1, const float* __restrict__ Wl1,
    const float* __restrict__ W2, const float* __restrict__ Wl2,
    const float* __restrict__ W3, const float* __restrict__ Wl3,
    const float* __restrict__ bl3,
    const float* __restrict__ nf, const int* __restrict__ ei,
    unsigned short* __restrict__ Wc1, unsigned short* __restrict__ Wc2,
    unsigned short* __restrict__ Bt3, float* __restrict__ biasc,
    unsigned short* __restrict__ Abf1, unsigned short* __restrict__ Abf2,
    int* __restrict__ deg, int Mpad, int N, int E)
{
  __shared__ unsigned short tile[32][33];
  int lb = blockIdx.x;
  if (lb < 512){ tr_tile(W1, Wc1, 512, 1024, 0, lb, tile); return; }
  lb -= 512;
  if (lb < 512){ tr_tile(Wl1, Wc1, 512, 1024, 1024, lb, tile); return; }
  lb -= 512;
  if (lb < 1024){ tr_tile(W2, Wc2, 1024, 1024, 0, lb, tile); return; }
  lb -= 1024;
  if (lb < 1024){ tr_tile(Wl2, Wc2, 1024, 1024, 1024, lb, tile); return; }
  lb -= 1024;
  if (lb < 512){              // w3fill: Bt3[128][1024] + biasc[48]
    int idx = lb * 256 + threadIdx.x;
    if (idx < 48) biasc[idx] = (idx >= 36 && idx < 42) ? bl3[idx - 36] : 0.f;
    int n = idx >> 10, k = idx & 1023;
    float v = 0.f;
    if (n < 36) v = W3[(size_t)k * 36 + n];
    else if (n < 42) v = Wl3[(size_t)k * 6 + (n - 36)];
    Bt3[idx] = f2bf(v);
    return;
  }
  lb -= 512;
  int cvtBlocks = Mpad >> 1;
  if (lb < cvtBlocks){        // nf fp32 [N,512] -> Abf1 bf16 [Mpad,512]
    int idx = lb * 256 + threadIdx.x;
    int e = idx << 2;
    int row = e >> 9;
    ushort4 o;
    if (row < N){
      float4 v = *(const float4*)(nf + (size_t)row * 512 + (e & 511));
      o.x = f2bf(v.x); o.y = f2bf(v.y); o.z = f2bf(v.z); o.w = f2bf(v.w);
    } else { o.x = o.y = o.z = o.w = 0; }
    *(ushort4*)(Abf1 + e) = o;
    return;
  }
  lb -= cvtBlocks;
  int padBlocks = Mpad - N;
  if (lb < padBlocks){        // zero Abf2 rows N..Mpad
    int idx = lb * 256 + threadIdx.x;
    ushort4 z; z.x = z.y = z.z = z.w = 0;
    *(ushort4*)(Abf2 + (size_t)N * 1024 + (size_t)idx * 4) = z;
    return;
  }
  lb -= padBlocks;
  int e = lb * 256 + threadIdx.x;   // degree count
  if (e < E) atomicAdd(&deg[ei[E + e]], 1);
}

// ---------------- CSR scan + scatter ----------------
__global__ void k_scan(const int* __restrict__ deg, int* __restrict__ rp,
                       int* __restrict__ cur, int n){
  __shared__ int part[1024];
  int t = threadIdx.x;
  int K = (n + 1023) >> 10;
  int vals[16];
  int start = t * K;
  int local = 0;
  for (int j = 0; j < K; j++){
    int idx = start + j;
    int v = (idx < n) ? deg[idx] : 0;
    vals[j] = local;
    local += v;
  }
  part[t] = local;
  __syncthreads();
  for (int off = 1; off < 1024; off <<= 1){
    int v = (t >= off) ? part[t - off] : 0;
    __syncthreads();
    part[t] += v;
    __syncthreads();
  }
  int base = part[t] - local;
  for (int j = 0; j < K; j++){
    int idx = start + j;
    if (idx < n){ rp[idx] = base + vals[j]; cur[idx] = base + vals[j]; }
  }
  if (t == 1023) rp[n] = part[1023];
}

__global__ void k_scatter(const int* __restrict__ ei, int* __restrict__ cur,
                          int* __restrict__ col, int E){
  int e = blockIdx.x * blockDim.x + threadIdx.x;
  if (e < E){
    int s = ei[e], d = ei[E + e];
    int p = atomicAdd(&cur[d], 1);
    col[p] = s;
  }
}

// ---------------- bf16 MFMA GEMM, 128x128 tile, BK=32, LDS XOR swizzle ------
// Counted-vmcnt TRIPLE-buffered k-loop, ONE barrier per k-step (48 KB LDS).
typedef __attribute__((ext_vector_type(8))) short bf8_t;
typedef __attribute__((ext_vector_type(4))) float f4_t;

__device__ __forceinline__ void async16(const unsigned short* g, unsigned short* l){
  __builtin_amdgcn_global_load_lds(
      (const __attribute__((address_space(1))) void*)g,
      (__attribute__((address_space(3))) void*)l, 16, 0, 0);
}

// grid: 8 * Gm * Ntiles (1D); xcd = b&7 owns m-tiles [xcd*Gm, ...)
// fpOut=0 (layers 1/2, Ntot=2048): bn<1024 -> outH fp8 + fused attn dots;
//   bn>=1024 -> outY bf16+bias.
// fpOut=1 (layer 3, Ntot=48): SPLIT-K x4; partials via atomicAdd into
//   pre-zeroed outF (comb) and alsv/aldv (als3/ald3).
__global__ __launch_bounds__(256) void k_mfma_gemm(
    const unsigned short* __restrict__ A,
    const unsigned short* __restrict__ Bt,
    const float* __restrict__ bias,
    unsigned char* __restrict__ outH,
    unsigned short* __restrict__ outY,
    float* __restrict__ outF,
    const float* __restrict__ asv, const float* __restrict__ adv,
    float* __restrict__ alsv, float* __restrict__ aldv,
    int M, int K, int Ntot, int Mtiles, int Gm, int fpOut)
{
  __shared__ unsigned short SM[3 * 8192];   // 48 KB: 3 x (A 8KB + B 8KB)
  int b = blockIdx.x;
  int xcd = b & 7;
  int j = b >> 3;
  int mloc = j % Gm;
  int n = j / Gm;
  int mtile = xcd * Gm + mloc;
  if (mtile >= Mtiles) return;
  int bm = mtile * 128;
  int sIdx = fpOut ? n : 0;          // split-K index for layer-3
  int bn   = fpOut ? 0 : n * 128;
  int Kc   = fpOut ? (K >> 2) : K;   // 4-way split for layer-3
  int kBeg = sIdx * Kc;

  int t = threadIdx.x;
  int w = t >> 6, lane = t & 63;
  int wm = (w >> 1) * 64, wn = (w & 1) * 64;
  int lr = lane & 15, lq = lane >> 4;

  f4_t acc[4][4] = {};

  int srow = lane >> 2;                                   // 0..15 in chunk
  int scol = (((lane & 3) ^ ((lane >> 3) & 3)) << 3);     // swizzled k-chunk
  int sw   = (lr >> 1) & 3;                               // read-side swizzle

  // one stage = EXACTLY 4 global_load_lds per thread (vmcnt accounting!)
  auto stage = [&](int bufOff, int k0){
#pragma unroll
    for (int r = 0; r < 2; r++){
      int c = r * 4 + w;
      async16(A + (size_t)(bm + c * 16 + srow) * K + k0 + scol,
              &SM[bufOff + c * 512]);
      async16(Bt + (size_t)(bn + c * 16 + srow) * K + k0 + scol,
              &SM[bufOff + 4096 + c * 512]);
    }
  };

  int nt = Kc >> 5;                  // BK = 32
  stage(0, kBeg);
  if (nt > 1) stage(8192, kBeg + 32);
  int cb = 0;                        // current buffer index = kt % 3
  for (int kt = 0; kt < nt; ++kt){
    if (kt + 1 < nt) { asm volatile("s_waitcnt vmcnt(4)" ::: "memory"); }
    else             { asm volatile("s_waitcnt vmcnt(0)" ::: "memory"); }
    // Single barrier: publishes stage(kt) writes AND proves buf[(kt-1)%3]
    // reads finished -> stage(kt+2) into it is WAR-safe.
    __builtin_amdgcn_s_barrier();
    if (kt + 2 < nt){
      int st = cb + 2; if (st >= 3) st -= 3;
      stage(st * 8192, kBeg + ((kt + 2) << 5));
    }
    int aOff = cb * 8192, bOff = aOff + 4096;
    bf8_t a[4], bfr[4];
#pragma unroll
    for (int i = 0; i < 4; i++)
      a[i] = *(const bf8_t*)&SM[aOff + (wm + i * 16 + lr) * 32 + (lq ^ sw) * 8];
#pragma unroll
    for (int i = 0; i < 4; i++)
      bfr[i] = *(const bf8_t*)&SM[bOff + (wn + i * 16 + lr) * 32 + (lq ^ sw) * 8];
#pragma unroll
    for (int mi = 0; mi < 4; mi++)
#pragma unroll
      for (int ni = 0; ni < 4; ni++)
        acc[mi][ni] = __builtin_amdgcn_mfma_f32_16x16x32_bf16(a[mi], bfr[ni], acc[mi][ni], 0, 0, 0);
    cb = cb + 1; if (cb == 3) cb = 0;
  }

  if (fpOut){
    __syncthreads();   // all waves done reading final k-tile from SM
    float* cl = (float*)SM;
#pragma unroll
    for (int mi = 0; mi < 4; mi++){
#pragma unroll
      for (int ni = 0; ni < 4; ni++){
        int colg = wn + ni * 16 + lr;
        if (colg >= Ntot) continue;
        float bv = (sIdx == 0) ? bias[colg] : 0.f;
#pragma unroll
        for (int rg = 0; rg < 4; rg++){
          int rowl = wm + mi * 16 + lq * 4 + rg;
          int rowg = bm + rowl;
          float v = acc[mi][ni][rg] + bv;
          cl[rowl * 49 + colg] = v;
          if (rowg < M) atomicAdd(&outF[(size_t)rowg * Ntot + colg], v);
        }
      }
    }
    __syncthreads();
    for (int task = t; task < 128 * 6; task += 256){
      int row = task / 6, h = task - row * 6;
      int rowg = bm + row;
      if (rowg < M){
        float s = 0.f, d = 0.f;
#pragma unroll
        for (int c = 0; c < 6; c++){
          float v = cl[row * 49 + h * 6 + c];
          s += v * asv[h * 6 + c];
          d += v * adv[h * 6 + c];
        }
        atomicAdd(&alsv[rowg * 6 + h], s);
        atomicAdd(&aldv[rowg * 6 + h], d);
      }
    }
  } else if (bn < 1024){
#pragma unroll
    for (int mi = 0; mi < 4; mi++){
#pragma unroll
      for (int ni = 0; ni < 4; ni++){
        int colg = bn + wn + ni * 16 + lr;
#pragma unroll
        for (int rg = 0; rg < 4; rg++){
          int rowg = bm + wm + mi * 16 + lq * 4 + rg;
          if (rowg < M) outH[(size_t)rowg * 1024 + colg] = f2fp8(acc[mi][ni][rg]);
        }
      }
    }
    int hd = bn >> 8;
    float wsc[4], wdc[4];
#pragma unroll
    for (int ni = 0; ni < 4; ni++){
      int colg = bn + wn + ni * 16 + lr;
      wsc[ni] = asv[colg];
      wdc[ni] = adv[colg];
    }
#pragma unroll
    for (int mi = 0; mi < 4; mi++){
#pragma unroll
      for (int rg = 0; rg < 4; rg++){
        float ps = 0.f, pd = 0.f;
#pragma unroll
        for (int ni = 0; ni < 4; ni++){
          float v = acc[mi][ni][rg];
          ps += v * wsc[ni];
          pd += v * wdc[ni];
        }
#pragma unroll
        for (int msk = 1; msk < 16; msk <<= 1){
          ps += __shfl_xor(ps, msk);
          pd += __shfl_xor(pd, msk);
        }
        int rowg = bm + wm + mi * 16 + lq * 4 + rg;
        if (lr == 0 && rowg < M){
          atomicAdd(&alsv[rowg * 4 + hd], ps);
          atomicAdd(&aldv[rowg * 4 + hd], pd);
        }
      }
    }
  } else {
#pragma unroll
    for (int mi = 0; mi < 4; mi++){
#pragma unroll
      for (int ni = 0; ni < 4; ni++){
        int colg = bn + wn + ni * 16 + lr - 1024;
        float bv = bias[colg];
#pragma unroll
        for (int rg = 0; rg < 4; rg++){
          int rowg = bm + wm + mi * 16 + lq * 4 + rg;
          if (rowg < M) outY[(size_t)rowg * 1024 + colg] = f2bf(acc[mi][ni][rg] + bv);
        }
      }
    }
  }
}

// ---------------- GAT aggregation (layers 1/2): WAVE-per-node, no LDS ------
// 4 nodes/block (one per 64-lane wave); zero barriers. Lane owns 4 cols in
// each head chunk (j*256 + lane*4). 2-deep prefetched gather (4x4B/edge).
__global__ __launch_bounds__(256) void k_agg(const unsigned char* __restrict__ Hq,
                                             const unsigned short* __restrict__ Y,
                                             unsigned short* __restrict__ Yout,
                                             const float* __restrict__ bias,
                                             const float* __restrict__ als,
                                             const float* __restrict__ ald,
                                             const int* __restrict__ rp,
                                             const int* __restrict__ col,
                                             int N){
  int t = threadIdx.x;
  int lane = t & 63;
  int i = blockIdx.x * 4 + (t >> 6);
  if (i >= N) return;
  int ro = rp[i];
  int deg = rp[i + 1] - ro;

  // ---- per-wave 4-head online softmax over edges ----
  float aldv[4], ef[4], m[4], s[4];
#pragma unroll
  for (int h = 0; h < 4; h++){
    aldv[h] = ald[i * 4 + h];
    ef[h] = leaky(als[i * 4 + h] + aldv[h]);
    m[h] = ef[h];
    s[h] = (lane == 0) ? 1.f : 0.f;   // self term counted once
  }
  for (int e = lane; e < deg; e += 64){
    int src = col[ro + e];
    float4 av = *(const float4*)(als + (size_t)src * 4);
    float evv[4] = { leaky(av.x + aldv[0]), leaky(av.y + aldv[1]),
                     leaky(av.z + aldv[2]), leaky(av.w + aldv[3]) };
#pragma unroll
    for (int h = 0; h < 4; h++){
      float M = fmaxf(m[h], evv[h]);
      s[h] = s[h] * __expf(m[h] - M) + __expf(evv[h] - M);
      m[h] = M;
    }
  }
#pragma unroll
  for (int off = 32; off >= 1; off >>= 1){
#pragma unroll
    for (int h = 0; h < 4; h++){
      float mo = __shfl_down(m[h], off);
      float so = __shfl_down(s[h], off);
      float M = fmaxf(m[h], mo);
      s[h] = s[h] * __expf(m[h] - M) + so * __expf(mo - M);
      m[h] = M;
    }
  }
  float inv[4];
#pragma unroll
  for (int h = 0; h < 4; h++){
    m[h] = __shfl(m[h], 0);
    s[h] = __shfl(s[h], 0);
    inv[h] = 1.f / (s[h] + 1e-16f);
  }

  // ---- accumulator init: Y + bias + self contribution ----
  float acc[4][4];
#pragma unroll
  for (int jh = 0; jh < 4; jh++){
    int off4 = jh * 256 + lane * 4;
    float4 yv = loadbf4(Y + (size_t)i * 1024 + off4);
    float4 bv = *(const float4*)(bias + off4);
    float asf = __expf(ef[jh] - m[jh]) * inv[jh];
    float4 hv = fp8x4(*(const unsigned int*)(Hq + (size_t)i * 1024 + off4));
    acc[jh][0] = yv.x + bv.x + asf * hv.x;
    acc[jh][1] = yv.y + bv.y + asf * hv.y;
    acc[jh][2] = yv.z + bv.z + asf * hv.z;
    acc[jh][3] = yv.w + bv.w + asf * hv.w;
  }

  // gather helpers
  auto LD4 = [&](int c) -> uint4 {
    const unsigned char* p = Hq + (size_t)c * 1024 + lane * 4;
    uint4 r;
    r.x = *(const unsigned int*)(p);
    r.y = *(const unsigned int*)(p + 256);
    r.z = *(const unsigned int*)(p + 512);
    r.w = *(const unsigned int*)(p + 768);
    return r;
  };
  auto ACC = [&](const uint4& g, int c){
    float4 av = *(const float4*)(als + (size_t)c * 4);
    float a0 = __expf(leaky(av.x + aldv[0]) - m[0]) * inv[0];
    float a1 = __expf(leaky(av.y + aldv[1]) - m[1]) * inv[1];
    float a2 = __expf(leaky(av.z + aldv[2]) - m[2]) * inv[2];
    float a3 = __expf(leaky(av.w + aldv[3]) - m[3]) * inv[3];
    float4 h0 = fp8x4(g.x), h1 = fp8x4(g.y), h2 = fp8x4(g.z), h3 = fp8x4(g.w);
    acc[0][0] += a0 * h0.x; acc[0][1] += a0 * h0.y; acc[0][2] += a0 * h0.z; acc[0][3] += a0 * h0.w;
    acc[1][0] += a1 * h1.x; acc[1][1] += a1 * h1.y; acc[1][2] += a1 * h1.z; acc[1][3] += a1 * h1.w;
    acc[2][0] += a2 * h2.x; acc[2][1] += a2 * h2.y; acc[2][2] += a2 * h2.z; acc[2][3] += a2 * h2.w;
    acc[3][0] += a3 * h3.x; acc[3][1] += a3 * h3.y; acc[3][2] += a3 * h3.z; acc[3][3] += a3 * h3.w;
  };

  // ---- 2-deep prefetched gather over edges ----
  int c0 = 0, c1 = 0;
  uint4 g0 = {0,0,0,0}, g1 = {0,0,0,0};
  if (deg > 0){ c0 = col[ro];     g0 = LD4(c0); }
  if (deg > 1){ c1 = col[ro + 1]; g1 = LD4(c1); }
  int e = 0;
  for (; e + 2 <= deg; e += 2){
    uint4 v0 = g0, v1 = g1;
    int d0 = c0, d1 = c1;
    if (e + 2 < deg){ c0 = col[ro + e + 2]; g0 = LD4(c0); }
    if (e + 3 < deg){ c1 = col[ro + e + 3]; g1 = LD4(c1); }
    ACC(v0, d0);
    ACC(v1, d1);
  }
  if (e < deg) ACC(g0, c0);   // odd tail: g0/c0 hold element e

  // ---- ELU + store ----
#pragma unroll
  for (int jh = 0; jh < 4; jh++){
    int off4 = jh * 256 + lane * 4;
    float x0 = acc[jh][0], x1 = acc[jh][1], x2 = acc[jh][2], x3 = acc[jh][3];
    x0 = x0 > 0.f ? x0 : expm1f(x0);
    x1 = x1 > 0.f ? x1 : expm1f(x1);
    x2 = x2 > 0.f ? x2 : expm1f(x2);
    x3 = x3 > 0.f ? x3 : expm1f(x3);
    ushort4 o;
    o.x = f2bf(x0); o.y = f2bf(x1); o.z = f2bf(x2); o.w = f2bf(x3);
    *(ushort4*)(Yout + (size_t)i * 1024 + off4) = o;
  }
}

// ---------------- layer 3: GAT(mean heads) + b3 + lin3 + log_softmax -------
// Alphas staged in LDS by 64 parallel lanes; 36-lane output loop is
// pure load+FMA with 2-deep comb prefetch.
__global__ __launch_bounds__(64) void k_layer3(const float* __restrict__ comb,
                                               const float* __restrict__ als,
                                               const float* __restrict__ ald,
                                               const float* __restrict__ b3,
                                               const int* __restrict__ rp,
                                               const int* __restrict__ col,
                                               float* __restrict__ out){
  int i = blockIdx.x;
  int lane = threadIdx.x;
  int ro = rp[i], deg = rp[i + 1] - ro;
  float aldv[6], m[6], s[6];
#pragma unroll
  for (int h = 0; h < 6; h++){
    aldv[h] = ald[i * 6 + h];
    float e = leaky(als[i * 6 + h] + aldv[h]);
    m[h] = e;
    s[h] = (lane == 0) ? 1.f : 0.f;
  }
  for (int e = lane; e < deg; e += 64){
    int src = col[ro + e];
#pragma unroll
    for (int h = 0; h < 6; h++){
      float ev = leaky(als[src * 6 + h] + aldv[h]);
      float M = fmaxf(m[h], ev);
      s[h] = s[h] * __expf(m[h] - M) + __expf(ev - M);
      m[h] = M;
    }
  }
#pragma unroll
  for (int off = 32; off >= 1; off >>= 1){
#pragma unroll
    for (int h = 0; h < 6; h++){
      float mo = __shfl_down(m[h], off);
      float so = __shfl_down(s[h], off);
      float M = fmaxf(m[h], mo);
      s[h] = s[h] * __expf(m[h] - M) + so * __expf(mo - M);
      m[h] = M;
    }
  }
#pragma unroll
  for (int h = 0; h < 6; h++){ m[h] = __shfl(m[h], 0); s[h] = __shfl(s[h], 0); }
  float invh[6];
#pragma unroll
  for (int h = 0; h < 6; h++) invh[h] = 1.f / (s[h] + 1e-16f);

  __shared__ float s_al3[64][6];
  __shared__ int   s_src3[64];
  __shared__ float o36[36];
  __shared__ float o6[6];

  int hh = lane / 6, cc = lane - hh * 6;
  (void)cc;
  float accv = 0.f;
  if (lane < 36)
    accv = __expf(leaky(als[i * 6 + hh] + aldv[hh]) - m[hh]) * invh[hh]
           * comb[(size_t)i * 48 + lane];

  for (int base = 0; base < deg; base += 64){
    __syncthreads();
    int e0 = base + lane;
    if (e0 < deg){
      int src = col[ro + e0];
      s_src3[lane] = src;
#pragma unroll
      for (int h = 0; h < 6; h++)
        s_al3[lane][h] = __expf(leaky(als[src * 6 + h] + aldv[h]) - m[h]) * invh[h];
    }
    __syncthreads();
    int nn = min(64, deg - base);
    if (lane < 36){
      // 2-deep comb prefetch; invariant: c0,c1 hold elements e, e+1.
      float c0 = 0.f, c1 = 0.f;
      if (nn > 0) c0 = comb[(size_t)s_src3[0] * 48 + lane];
      if (nn > 1) c1 = comb[(size_t)s_src3[1] * 48 + lane];
      int e = 0;
      for (; e + 2 <= nn; e += 2){
        float a0 = s_al3[e][hh], a1 = s_al3[e + 1][hh];
        float v0 = c0, v1 = c1;
        if (e + 2 < nn) c0 = comb[(size_t)s_src3[e + 2] * 48 + lane];
        if (e + 3 < nn) c1 = comb[(size_t)s_src3[e + 3] * 48 + lane];
        accv += a0 * v0 + a1 * v1;
      }
      if (e < nn) accv += s_al3[e][hh] * c0;
    }
  }
  __syncthreads();
  if (lane < 36) o36[lane] = accv;
  __syncthreads();
  if (lane < 6){
    float v = 0.f;
#pragma unroll
    for (int h = 0; h < 6; h++) v += o36[h * 6 + lane];
    o6[lane] = v * (1.f / 6.f) + b3[lane] + comb[(size_t)i * 48 + 36 + lane];
  }
  __syncthreads();
  if (lane == 0){
    float mx = o6[0];
    for (int c = 1; c < 6; c++) mx = fmaxf(mx, o6[c]);
    float se = 0.f;
    for (int c = 0; c < 6; c++) se += __expf(o6[c] - mx);
    float lse = logf(se);
    for (int c = 0; c < 6; c++) out[(size_t)i * 6 + c] = o6[c] - mx - lse;
  }
}

// ---------------------------------------------------------------------------
extern "C" void kernel_launch(void* const* d_in, const int* in_sizes, int n_in,
                              void* d_out, int out_size, void* d_ws, size_t ws_size,
                              hipStream_t stream){
  const float* nf  = (const float*)d_in[0];
  const int*   ei  = (const int*)d_in[1];
  const float* W1  = (const float*)d_in[2];
  const float* as1 = (const float*)d_in[3];
  const float* ad1 = (const float*)d_in[4];
  const float* b1  = (const float*)d_in[5];
  const float* Wl1 = (const float*)d_in[6];
  const float* bl1 = (const float*)d_in[7];
  const float* W2  = (const float*)d_in[8];
  const float* as2 = (const float*)d_in[9];
  const float* ad2 = (const float*)d_in[10];
  const float* b2  = (const float*)d_in[11];
  const float* Wl2 = (const float*)d_in[12];
  const float* bl2 = (const float*)d_in[13];
  const float* W3  = (const float*)d_in[14];
  const float* as3 = (const float*)d_in[15];
  const float* ad3 = (const float*)d_in[16];
  const float* b3  = (const float*)d_in[17];
  const float* Wl3 = (const float*)d_in[18];
  const float* bl3 = (const float*)d_in[19];
  float* out = (float*)d_out;

  const int N = in_sizes[0] / 512;   // 10000
  const int E = in_sizes[1] / 2;     // 160000
  const int Mpad = ((N + 127) / 128) * 128;   // 10112
  const int Mtiles = Mpad / 128;              // 79
  const int Gm = (Mtiles + 7) / 8;            // 10

  char* ws = (char*)d_ws;
  size_t off = 0;
  auto alloc = [&](size_t bytes) -> char* {
    char* p = ws + off;
    off += (bytes + 255) & ~(size_t)255;
    return p;
  };
  unsigned short* Abf1 = (unsigned short*)alloc((size_t)Mpad * 512 * 2);
  unsigned short* Abf2 = (unsigned short*)alloc((size_t)Mpad * 1024 * 2);
  unsigned char*  Hq   = (unsigned char*)alloc((size_t)N * 1024);
  unsigned short* Ybf  = (unsigned short*)alloc((size_t)N * 1024 * 2);
  // contiguous zero region: deg + (als,ald) a/b pairs + als3/ald3 + comb
  size_t zbytes = (size_t)N * 4            // deg
                + 4 * (size_t)N * 4 * 4    // als_a, ald_a, als_b, ald_b
                + 2 * (size_t)N * 6 * 4    // als3, ald3 (atomic-accumulated)
                + (size_t)N * 48 * 4;      // comb (atomic-accumulated, split-K)
  char*  zbase  = alloc(zbytes);
  int*   deg    = (int*)zbase;
  float* als_a  = (float*)(zbase + (size_t)N * 4);
  float* ald_a  = als_a + (size_t)N * 4;
  float* als_b  = ald_a + (size_t)N * 4;
  float* ald_b  = als_b + (size_t)N * 4;
  float* als3   = ald_b + (size_t)N * 4;
  float* ald3   = als3 + (size_t)N * 6;
  float* comb   = ald3 + (size_t)N * 6;
  float* biasc  = (float*)alloc(48 * 4);
  int* rp       = (int*)alloc((size_t)(N + 1) * 4);
  int* cur      = (int*)alloc((size_t)N * 4);
  int* colx     = (int*)alloc((size_t)E * 4);
  unsigned short* Wc1 = (unsigned short*)alloc((size_t)2048 * 512 * 2);
  unsigned short* Wc2 = (unsigned short*)alloc((size_t)2048 * 1024 * 2);
  unsigned short* Bt3 = (unsigned short*)alloc((size_t)128 * 1024 * 2);

  hipMemsetAsync(zbase, 0, zbytes, stream);

  int prepBlocks = 512 + 512 + 1024 + 1024 + 512 + (Mpad >> 1) + (Mpad - N)
                 + (E + 255) / 256;
  k_prep<<<prepBlocks, 256, 0, stream>>>(W1, Wl1, W2, Wl2, W3, Wl3, bl3,
                                         nf, ei, Wc1, Wc2, Bt3, biasc,
                                         Abf1, Abf2, deg, Mpad, N, E);
  k_scan   <<<1, 1024, 0, stream>>>(deg, rp, cur, N);
  k_scatter<<<(E + 255) / 256, 256, 0, stream>>>(ei, cur, colx, E);

  int blocksL = 8 * Gm * 16;
  int blocks3 = 8 * Gm * 4;          // split-K x4
  int aggBlocks = (N + 3) / 4;       // wave-per-node

  // layer 1 (attn dots fused into GEMM epilogue -> als_a/ald_a)
  k_mfma_gemm<<<blocksL, 256, 0, stream>>>(Abf1, Wc1, bl1, Hq, Ybf, nullptr,
                                           as1, ad1, als_a, ald_a,
                                           N, 512, 2048, Mtiles, Gm, 0);
  k_agg<<<aggBlocks, 256, 0, stream>>>(Hq, Ybf, Abf2, b1, als_a, ald_a, rp, colx, N);

  // layer 2 (dots -> als_b/ald_b, pre-zeroed; no mid-stream memset)
  k_mfma_gemm<<<blocksL, 256, 0, stream>>>(Abf2, Wc2, bl2, Hq, Ybf, nullptr,
                                           as2, ad2, als_b, ald_b,
                                           N, 1024, 2048, Mtiles, Gm, 0);
  k_agg<<<aggBlocks, 256, 0, stream>>>(Hq, Ybf, Abf2, b2, als_b, ald_b, rp, colx, N);

  // layer 3 (split-K x4; partial comb/als3/ald3 via atomics, pre-zeroed)
  k_mfma_gemm<<<blocks3, 256, 0, stream>>>(Abf2, Bt3, biasc, nullptr, nullptr, comb,
                                           as3, ad3, als3, ald3,
                                           N, 1024, 48, Mtiles, Gm, 1);
  k_layer3<<<N, 64, 0, stream>>>(comb, als3, ald3, b3, rp, colx, out);
}

// Round 22
// 366.173 us; speedup vs baseline: 1.0568x; 1.0568x over previous
//
#include <hip/hip_runtime.h>
#include <math.h>

// ---------------------------------------------------------------------------
// GAT 3-layer net. R34 = REVERT to R30 (best verified: 367.6 us).
// R33 post-mortem: wave-per-node k_agg moved 4 exps/edge INTO the serial
// gather loop (R30 staged them 64-lane-parallel in LDS, amortized over 256
// threads) -> +19.4 us regression. Barrier overhead in k_agg is NOT the
// bottleneck; block-per-node staging is the better structure. Reverted.
// Configuration (all measured wins):
//  - BK=32 3-buffer/1-barrier counted-vmcnt MFMA GEMM (R24/R25), 128x128
//    tile, XOR LDS swizzle (0 conflicts), XCD grid swizzle, fp8 H.
//  - Fused attn dots in GEMM epilogues (L1/L2 register-level, L3 LDS).
//  - GEMM3 split-K x4 with atomics into pre-zeroed comb/als3/ald3 (R23).
//  - k_agg block-per-node, LDS alpha staging, 4-deep prefetched gather (R30).
//  - k_layer3 parallel-alpha LDS staging + 2-deep comb prefetch (R30).
// ---------------------------------------------------------------------------

__device__ __forceinline__ float leaky(float x){ return x > 0.f ? x : 0.2f * x; }

__device__ __forceinline__ float bf2f(unsigned short u){
  union { unsigned int i; float f; } v; v.i = ((unsigned int)u) << 16; return v.f;
}
__device__ __forceinline__ unsigned short f2bf(float f){
  union { float f; unsigned int i; } v; v.f = f;
  unsigned int r = v.i + 0x7FFF + ((v.i >> 16) & 1);   // RNE
  return (unsigned short)(r >> 16);
}
__device__ __forceinline__ float4 loadbf4(const unsigned short* p){
  ushort4 u = *(const ushort4*)p;
  return make_float4(bf2f(u.x), bf2f(u.y), bf2f(u.z), bf2f(u.w));
}

// ---- fp8 e4m3 helpers (HW cvt; self-consistent round-trip) ----
typedef __attribute__((ext_vector_type(2))) float f2v;
__device__ __forceinline__ unsigned char f2fp8(float x){
  int v = __builtin_amdgcn_cvt_pk_fp8_f32(x, x, 0, false);
  return (unsigned char)(v & 0xff);
}
__device__ __forceinline__ float4 fp8x4(unsigned int u){
  f2v a = __builtin_amdgcn_cvt_pk_f32_fp8((int)u, false);
  f2v b = __builtin_amdgcn_cvt_pk_f32_fp8((int)u, true);
  return make_float4(a.x, a.y, b.x, b.y);
}

// ---------------- mega prep kernel ----------------
__device__ __forceinline__ void tr_tile(const float* __restrict__ W,
                                        unsigned short* __restrict__ Wt,
                                        int K, int N, int rowOff, int lb,
                                        unsigned short tile[32][33]){
  int gx = K >> 5;
  int bk = (lb % gx) << 5;
  int bn = (lb / gx) << 5;
  int tx = threadIdx.x & 31;
  int ty = threadIdx.x >> 5;
#pragma unroll
  for (int r = 0; r < 32; r += 8)
    tile[ty + r][tx] = f2bf(W[(size_t)(bk + ty + r) * N + bn + tx]);
  __syncthreads();
#pragma unroll
  for (int r = 0; r < 32; r += 8)
    Wt[(size_t)(rowOff + bn + ty + r) * K + bk + tx] = tile[tx][ty + r];
}

__global__ __launch_bounds__(256) void k_prep(
    const float* __restrict__ W1, const float* __restrict__ Wl1,
    const float* __restrict__ W2, const float* __restrict__ Wl2,
    const float* __restrict__ W3, const float* __restrict__ Wl3,
    const float* __restrict__ bl3,
    const float* __restrict__ nf, const int* __restrict__ ei,
    unsigned short* __restrict__ Wc1, unsigned short* __restrict__ Wc2,
    unsigned short* __restrict__ Bt3, float* __restrict__ biasc,
    unsigned short* __restrict__ Abf1, unsigned short* __restrict__ Abf2,
    int* __restrict__ deg, int Mpad, int N, int E)
{
  __shared__ unsigned short tile[32][33];
  int lb = blockIdx.x;
  if (lb < 512){ tr_tile(W1, Wc1, 512, 1024, 0, lb, tile); return; }
  lb -= 512;
  if (lb < 512){ tr_tile(Wl1, Wc1, 512, 1024, 1024, lb, tile); return; }
  lb -= 512;
  if (lb < 1024){ tr_tile(W2, Wc2, 1024, 1024, 0, lb, tile); return; }
  lb -= 1024;
  if (lb < 1024){ tr_tile(Wl2, Wc2, 1024, 1024, 1024, lb, tile); return; }
  lb -= 1024;
  if (lb < 512){              // w3fill: Bt3[128][1024] + biasc[48]
    int idx = lb * 256 + threadIdx.x;
    if (idx < 48) biasc[idx] = (idx >= 36 && idx < 42) ? bl3[idx - 36] : 0.f;
    int n = idx >> 10, k = idx & 1023;
    float v = 0.f;
    if (n < 36) v = W3[(size_t)k * 36 + n];
    else if (n < 42) v = Wl3[(size_t)k * 6 + (n - 36)];
    Bt3[idx] = f2bf(v);
    return;
  }
  lb -= 512;
  int cvtBlocks = Mpad >> 1;
  if (lb < cvtBlocks){        // nf fp32 [N,512] -> Abf1 bf16 [Mpad,512]
    int idx = lb * 256 + threadIdx.x;
    int e = idx << 2;
    int row = e >> 9;
    ushort4 o;
    if (row < N){
      float4 v = *(const float4*)(nf + (size_t)row * 512 + (e & 511));
      o.x = f2bf(v.x); o.y = f2bf(v.y); o.z = f2bf(v.z); o.w = f2bf(v.w);
    } else { o.x = o.y = o.z = o.w = 0; }
    *(ushort4*)(Abf1 + e) = o;
    return;
  }
  lb -= cvtBlocks;
  int padBlocks = Mpad - N;
  if (lb < padBlocks){        // zero Abf2 rows N..Mpad
    int idx = lb * 256 + threadIdx.x;
    ushort4 z; z.x = z.y = z.z = z.w = 0;
    *(ushort4*)(Abf2 + (size_t)N * 1024 + (size_t)idx * 4) = z;
    return;
  }
  lb -= padBlocks;
  int e = lb * 256 + threadIdx.x;   // degree count
  if (e < E) atomicAdd(&deg[ei[E + e]], 1);
}

// ---------------- CSR scan + scatter ----------------
__global__ void k_scan(const int* __restrict__ deg, int* __restrict__ rp,
                       int* __restrict__ cur, int n){
  __shared__ int part[1024];
  int t = threadIdx.x;
  int K = (n + 1023) >> 10;
  int vals[16];
  int start = t * K;
  int local = 0;
  for (int j = 0; j < K; j++){
    int idx = start + j;
    int v = (idx < n) ? deg[idx] : 0;
    vals[j] = local;
    local += v;
  }
  part[t] = local;
  __syncthreads();
  for (int off = 1; off < 1024; off <<= 1){
    int v = (t >= off) ? part[t - off] : 0;
    __syncthreads();
    part[t] += v;
    __syncthreads();
  }
  int base = part[t] - local;
  for (int j = 0; j < K; j++){
    int idx = start + j;
    if (idx < n){ rp[idx] = base + vals[j]; cur[idx] = base + vals[j]; }
  }
  if (t == 1023) rp[n] = part[1023];
}

__global__ void k_scatter(const int* __restrict__ ei, int* __restrict__ cur,
                          int* __restrict__ col, int E){
  int e = blockIdx.x * blockDim.x + threadIdx.x;
  if (e < E){
    int s = ei[e], d = ei[E + e];
    int p = atomicAdd(&cur[d], 1);
    col[p] = s;
  }
}

// ---------------- bf16 MFMA GEMM, 128x128 tile, BK=32, LDS XOR swizzle ------
// Counted-vmcnt TRIPLE-buffered k-loop, ONE barrier per k-step (48 KB LDS).
typedef __attribute__((ext_vector_type(8))) short bf8_t;
typedef __attribute__((ext_vector_type(4))) float f4_t;

__device__ __forceinline__ void async16(const unsigned short* g, unsigned short* l){
  __builtin_amdgcn_global_load_lds(
      (const __attribute__((address_space(1))) void*)g,
      (__attribute__((address_space(3))) void*)l, 16, 0, 0);
}

// grid: 8 * Gm * Ntiles (1D); xcd = b&7 owns m-tiles [xcd*Gm, ...)
// fpOut=0 (layers 1/2, Ntot=2048): bn<1024 -> outH fp8 + fused attn dots;
//   bn>=1024 -> outY bf16+bias.
// fpOut=1 (layer 3, Ntot=48): SPLIT-K x4; partials via atomicAdd into
//   pre-zeroed outF (comb) and alsv/aldv (als3/ald3).
__global__ __launch_bounds__(256) void k_mfma_gemm(
    const unsigned short* __restrict__ A,
    const unsigned short* __restrict__ Bt,
    const float* __restrict__ bias,
    unsigned char* __restrict__ outH,
    unsigned short* __restrict__ outY,
    float* __restrict__ outF,
    const float* __restrict__ asv, const float* __restrict__ adv,
    float* __restrict__ alsv, float* __restrict__ aldv,
    int M, int K, int Ntot, int Mtiles, int Gm, int fpOut)
{
  __shared__ unsigned short SM[3 * 8192];   // 48 KB: 3 x (A 8KB + B 8KB)
  int b = blockIdx.x;
  int xcd = b & 7;
  int j = b >> 3;
  int mloc = j % Gm;
  int n = j / Gm;
  int mtile = xcd * Gm + mloc;
  if (mtile >= Mtiles) return;
  int bm = mtile * 128;
  int sIdx = fpOut ? n : 0;          // split-K index for layer-3
  int bn   = fpOut ? 0 : n * 128;
  int Kc   = fpOut ? (K >> 2) : K;   // 4-way split for layer-3
  int kBeg = sIdx * Kc;

  int t = threadIdx.x;
  int w = t >> 6, lane = t & 63;
  int wm = (w >> 1) * 64, wn = (w & 1) * 64;
  int lr = lane & 15, lq = lane >> 4;

  f4_t acc[4][4] = {};

  int srow = lane >> 2;                                   // 0..15 in chunk
  int scol = (((lane & 3) ^ ((lane >> 3) & 3)) << 3);     // swizzled k-chunk
  int sw   = (lr >> 1) & 3;                               // read-side swizzle

  // one stage = EXACTLY 4 global_load_lds per thread (vmcnt accounting!)
  auto stage = [&](int bufOff, int k0){
#pragma unroll
    for (int r = 0; r < 2; r++){
      int c = r * 4 + w;
      async16(A + (size_t)(bm + c * 16 + srow) * K + k0 + scol,
              &SM[bufOff + c * 512]);
      async16(Bt + (size_t)(bn + c * 16 + srow) * K + k0 + scol,
              &SM[bufOff + 4096 + c * 512]);
    }
  };

  int nt = Kc >> 5;                  // BK = 32
  stage(0, kBeg);
  if (nt > 1) stage(8192, kBeg + 32);
  int cb = 0;                        // current buffer index = kt % 3
  for (int kt = 0; kt < nt; ++kt){
    if (kt + 1 < nt) { asm volatile("s_waitcnt vmcnt(4)" ::: "memory"); }
    else             { asm volatile("s_waitcnt vmcnt(0)" ::: "memory"); }
    // Single barrier: publishes stage(kt) writes AND proves buf[(kt-1)%3]
    // reads finished -> stage(kt+2) into it is WAR-safe.
    __builtin_amdgcn_s_barrier();
    if (kt + 2 < nt){
      int st = cb + 2; if (st >= 3) st -= 3;
      stage(st * 8192, kBeg + ((kt + 2) << 5));
    }
    int aOff = cb * 8192, bOff = aOff + 4096;
    bf8_t a[4], bfr[4];
#pragma unroll
    for (int i = 0; i < 4; i++)
      a[i] = *(const bf8_t*)&SM[aOff + (wm + i * 16 + lr) * 32 + (lq ^ sw) * 8];
#pragma unroll
    for (int i = 0; i < 4; i++)
      bfr[i] = *(const bf8_t*)&SM[bOff + (wn + i * 16 + lr) * 32 + (lq ^ sw) * 8];
#pragma unroll
    for (int mi = 0; mi < 4; mi++)
#pragma unroll
      for (int ni = 0; ni < 4; ni++)
        acc[mi][ni] = __builtin_amdgcn_mfma_f32_16x16x32_bf16(a[mi], bfr[ni], acc[mi][ni], 0, 0, 0);
    cb = cb + 1; if (cb == 3) cb = 0;
  }

  if (fpOut){
    __syncthreads();   // all waves done reading final k-tile from SM
    float* cl = (float*)SM;
#pragma unroll
    for (int mi = 0; mi < 4; mi++){
#pragma unroll
      for (int ni = 0; ni < 4; ni++){
        int colg = wn + ni * 16 + lr;
        if (colg >= Ntot) continue;
        float bv = (sIdx == 0) ? bias[colg] : 0.f;
#pragma unroll
        for (int rg = 0; rg < 4; rg++){
          int rowl = wm + mi * 16 + lq * 4 + rg;
          int rowg = bm + rowl;
          float v = acc[mi][ni][rg] + bv;
          cl[rowl * 49 + colg] = v;
          if (rowg < M) atomicAdd(&outF[(size_t)rowg * Ntot + colg], v);
        }
      }
    }
    __syncthreads();
    for (int task = t; task < 128 * 6; task += 256){
      int row = task / 6, h = task - row * 6;
      int rowg = bm + row;
      if (rowg < M){
        float s = 0.f, d = 0.f;
#pragma unroll
        for (int c = 0; c < 6; c++){
          float v = cl[row * 49 + h * 6 + c];
          s += v * asv[h * 6 + c];
          d += v * adv[h * 6 + c];
        }
        atomicAdd(&alsv[rowg * 6 + h], s);
        atomicAdd(&aldv[rowg * 6 + h], d);
      }
    }
  } else if (bn < 1024){
#pragma unroll
    for (int mi = 0; mi < 4; mi++){
#pragma unroll
      for (int ni = 0; ni < 4; ni++){
        int colg = bn + wn + ni * 16 + lr;
#pragma unroll
        for (int rg = 0; rg < 4; rg++){
          int rowg = bm + wm + mi * 16 + lq * 4 + rg;
          if (rowg < M) outH[(size_t)rowg * 1024 + colg] = f2fp8(acc[mi][ni][rg]);
        }
      }
    }
    int hd = bn >> 8;
    float wsc[4], wdc[4];
#pragma unroll
    for (int ni = 0; ni < 4; ni++){
      int colg = bn + wn + ni * 16 + lr;
      wsc[ni] = asv[colg];
      wdc[ni] = adv[colg];
    }
#pragma unroll
    for (int mi = 0; mi < 4; mi++){
#pragma unroll
      for (int rg = 0; rg < 4; rg++){
        float ps = 0.f, pd = 0.f;
#pragma unroll
        for (int ni = 0; ni < 4; ni++){
          float v = acc[mi][ni][rg];
          ps += v * wsc[ni];
          pd += v * wdc[ni];
        }
#pragma unroll
        for (int msk = 1; msk < 16; msk <<= 1){
          ps += __shfl_xor(ps, msk);
          pd += __shfl_xor(pd, msk);
        }
        int rowg = bm + wm + mi * 16 + lq * 4 + rg;
        if (lr == 0 && rowg < M){
          atomicAdd(&alsv[rowg * 4 + hd], ps);
          atomicAdd(&aldv[rowg * 4 + hd], pd);
        }
      }
    }
  } else {
#pragma unroll
    for (int mi = 0; mi < 4; mi++){
#pragma unroll
      for (int ni = 0; ni < 4; ni++){
        int colg = bn + wn + ni * 16 + lr - 1024;
        float bv = bias[colg];
#pragma unroll
        for (int rg = 0; rg < 4; rg++){
          int rowg = bm + wm + mi * 16 + lq * 4 + rg;
          if (rowg < M) outY[(size_t)rowg * 1024 + colg] = f2bf(acc[mi][ni][rg] + bv);
        }
      }
    }
  }
}

// ---------------- GAT aggregation (layers 1/2): fp8 H gather + bf16 Y ------
// Block-per-node; LDS alpha staging (64-lane parallel); 4-deep prefetched
// gather (named regs, invariant tail). R30-verified structure.
__global__ __launch_bounds__(256) void k_agg(const unsigned char* __restrict__ Hq,
                                             const unsigned short* __restrict__ Y,
                                             unsigned short* __restrict__ Yout,
                                             const float* __restrict__ bias,
                                             const float* __restrict__ als,
                                             const float* __restrict__ ald,
                                             const int* __restrict__ rp,
                                             const int* __restrict__ col){
  int i = blockIdx.x;
  int t = threadIdx.x;
  int lane = t & 63;
  int w = t >> 6;           // head
  int ro = rp[i];
  int deg = rp[i + 1] - ro;
  __shared__ float sm[4], sinv[4], sald[4];
  __shared__ float s_alpha[64][4];
  __shared__ int s_src[64];

  float aldw = ald[i * 4 + w];
  float eself = leaky(als[i * 4 + w] + aldw);
  float m = eself;
  float s = (lane == 0) ? 1.f : 0.f;
  for (int e = lane; e < deg; e += 64){
    int src = col[ro + e];
    float ev = leaky(als[src * 4 + w] + aldw);
    float M = fmaxf(m, ev);
    s = s * __expf(m - M) + __expf(ev - M);
    m = M;
  }
#pragma unroll
  for (int off = 32; off >= 1; off >>= 1){
    float mo = __shfl_down(m, off);
    float so = __shfl_down(s, off);
    float M = fmaxf(m, mo);
    s = s * __expf(m - M) + so * __expf(mo - M);
    m = M;
  }
  if (lane == 0){ sm[w] = m; sinv[w] = 1.f / (s + 1e-16f); sald[w] = aldw; }
  __syncthreads();

  float mh = sm[w];
  float inv = sinv[w];
  float4 acc = loadbf4(Y + (size_t)i * 1024 + t * 4);
  float4 bb  = *(const float4*)(bias + t * 4);
  acc.x += bb.x; acc.y += bb.y; acc.z += bb.z; acc.w += bb.w;
  float aself = __expf(eself - mh) * inv;
  {
    float4 hv = fp8x4(*(const unsigned int*)(Hq + (size_t)i * 1024 + t * 4));
    acc.x += aself * hv.x; acc.y += aself * hv.y;
    acc.z += aself * hv.z; acc.w += aself * hv.w;
  }
  for (int base = 0; base < deg; base += 64){
    __syncthreads();
    int e0 = base + lane;
    if (e0 < deg){
      int src = col[ro + e0];             // redundant across waves; L1-cached
      if (t < 64) s_src[t] = src;
      s_alpha[lane][w] = __expf(leaky(als[src * 4 + w] + sald[w]) - sm[w]) * sinv[w];
    }
    __syncthreads();
    int nn = min(64, deg - base);
    // 4-deep prefetched gather. Invariant at loop top: u0..u3 hold
    // elements e, e+1, e+2, e+3 (those that are < nn).
    unsigned int u0 = 0, u1 = 0, u2 = 0, u3 = 0;
    if (nn > 0) u0 = *(const unsigned int*)(Hq + (size_t)s_src[0] * 1024 + t * 4);
    if (nn > 1) u1 = *(const unsigned int*)(Hq + (size_t)s_src[1] * 1024 + t * 4);
    if (nn > 2) u2 = *(const unsigned int*)(Hq + (size_t)s_src[2] * 1024 + t * 4);
    if (nn > 3) u3 = *(const unsigned int*)(Hq + (size_t)s_src[3] * 1024 + t * 4);
    int e = 0;
    for (; e + 4 <= nn; e += 4){
      float a0 = s_alpha[e][w],     a1 = s_alpha[e + 1][w];
      float a2 = s_alpha[e + 2][w], a3 = s_alpha[e + 3][w];
      float4 h0 = fp8x4(u0), h1 = fp8x4(u1), h2 = fp8x4(u2), h3 = fp8x4(u3);
      if (e + 4 < nn) u0 = *(const unsigned int*)(Hq + (size_t)s_src[e + 4] * 1024 + t * 4);
      if (e + 5 < nn) u1 = *(const unsigned int*)(Hq + (size_t)s_src[e + 5] * 1024 + t * 4);
      if (e + 6 < nn) u2 = *(const unsigned int*)(Hq + (size_t)s_src[e + 6] * 1024 + t * 4);
      if (e + 7 < nn) u3 = *(const unsigned int*)(Hq + (size_t)s_src[e + 7] * 1024 + t * 4);
      acc.x += a0 * h0.x + a1 * h1.x + a2 * h2.x + a3 * h3.x;
      acc.y += a0 * h0.y + a1 * h1.y + a2 * h2.y + a3 * h3.y;
      acc.z += a0 * h0.z + a1 * h1.z + a2 * h2.z + a3 * h3.z;
      acc.w += a0 * h0.w + a1 * h1.w + a2 * h2.w + a3 * h3.w;
    }
    // tail: 0..3 elements remain; u0..u2 hold e, e+1, e+2.
    if (e < nn){
      float a = s_alpha[e][w]; float4 hv = fp8x4(u0);
      acc.x += a * hv.x; acc.y += a * hv.y; acc.z += a * hv.z; acc.w += a * hv.w;
    }
    if (e + 1 < nn){
      float a = s_alpha[e + 1][w]; float4 hv = fp8x4(u1);
      acc.x += a * hv.x; acc.y += a * hv.y; acc.z += a * hv.z; acc.w += a * hv.w;
    }
    if (e + 2 < nn){
      float a = s_alpha[e + 2][w]; float4 hv = fp8x4(u2);
      acc.x += a * hv.x; acc.y += a * hv.y; acc.z += a * hv.z; acc.w += a * hv.w;
    }
  }
  acc.x = acc.x > 0.f ? acc.x : expm1f(acc.x);
  acc.y = acc.y > 0.f ? acc.y : expm1f(acc.y);
  acc.z = acc.z > 0.f ? acc.z : expm1f(acc.z);
  acc.w = acc.w > 0.f ? acc.w : expm1f(acc.w);
  ushort4 o;
  o.x = f2bf(acc.x); o.y = f2bf(acc.y); o.z = f2bf(acc.z); o.w = f2bf(acc.w);
  *(ushort4*)(Yout + (size_t)i * 1024 + t * 4) = o;
}

// ---------------- layer 3: GAT(mean heads) + b3 + lin3 + log_softmax -------
// Alphas staged in LDS by 64 parallel lanes; 36-lane output loop is
// pure load+FMA with 2-deep comb prefetch.
__global__ __launch_bounds__(64) void k_layer3(const float* __restrict__ comb,
                                               const float* __restrict__ als,
                                               const float* __restrict__ ald,
                                               const float* __restrict__ b3,
                                               const int* __restrict__ rp,
                                               const int* __restrict__ col,
                                               float* __restrict__ out){
  int i = blockIdx.x;
  int lane = threadIdx.x;
  int ro = rp[i], deg = rp[i + 1] - ro;
  float aldv[6], m[6], s[6];
#pragma unroll
  for (int h = 0; h < 6; h++){
    aldv[h] = ald[i * 6 + h];
    float e = leaky(als[i * 6 + h] + aldv[h]);
    m[h] = e;
    s[h] = (lane == 0) ? 1.f : 0.f;
  }
  for (int e = lane; e < deg; e += 64){
    int src = col[ro + e];
#pragma unroll
    for (int h = 0; h < 6; h++){
      float ev = leaky(als[src * 6 + h] + aldv[h]);
      float M = fmaxf(m[h], ev);
      s[h] = s[h] * __expf(m[h] - M) + __expf(ev - M);
      m[h] = M;
    }
  }
#pragma unroll
  for (int off = 32; off >= 1; off >>= 1){
#pragma unroll
    for (int h = 0; h < 6; h++){
      float mo = __shfl_down(m[h], off);
      float so = __shfl_down(s[h], off);
      float M = fmaxf(m[h], mo);
      s[h] = s[h] * __expf(m[h] - M) + so * __expf(mo - M);
      m[h] = M;
    }
  }
#pragma unroll
  for (int h = 0; h < 6; h++){ m[h] = __shfl(m[h], 0); s[h] = __shfl(s[h], 0); }
  float invh[6];
#pragma unroll
  for (int h = 0; h < 6; h++) invh[h] = 1.f / (s[h] + 1e-16f);

  __shared__ float s_al3[64][6];
  __shared__ int   s_src3[64];
  __shared__ float o36[36];
  __shared__ float o6[6];

  int hh = lane / 6, cc = lane - hh * 6;
  (void)cc;
  float accv = 0.f;
  if (lane < 36)
    accv = __expf(leaky(als[i * 6 + hh] + aldv[hh]) - m[hh]) * invh[hh]
           * comb[(size_t)i * 48 + lane];

  for (int base = 0; base < deg; base += 64){
    __syncthreads();
    int e0 = base + lane;
    if (e0 < deg){
      int src = col[ro + e0];
      s_src3[lane] = src;
#pragma unroll
      for (int h = 0; h < 6; h++)
        s_al3[lane][h] = __expf(leaky(als[src * 6 + h] + aldv[h]) - m[h]) * invh[h];
    }
    __syncthreads();
    int nn = min(64, deg - base);
    if (lane < 36){
      // 2-deep comb prefetch; invariant: c0,c1 hold elements e, e+1.
      float c0 = 0.f, c1 = 0.f;
      if (nn > 0) c0 = comb[(size_t)s_src3[0] * 48 + lane];
      if (nn > 1) c1 = comb[(size_t)s_src3[1] * 48 + lane];
      int e = 0;
      for (; e + 2 <= nn; e += 2){
        float a0 = s_al3[e][hh], a1 = s_al3[e + 1][hh];
        float v0 = c0, v1 = c1;
        if (e + 2 < nn) c0 = comb[(size_t)s_src3[e + 2] * 48 + lane];
        if (e + 3 < nn) c1 = comb[(size_t)s_src3[e + 3] * 48 + lane];
        accv += a0 * v0 + a1 * v1;
      }
      if (e < nn) accv += s_al3[e][hh] * c0;
    }
  }
  __syncthreads();
  if (lane < 36) o36[lane] = accv;
  __syncthreads();
  if (lane < 6){
    float v = 0.f;
#pragma unroll
    for (int h = 0; h < 6; h++) v += o36[h * 6 + lane];
    o6[lane] = v * (1.f / 6.f) + b3[lane] + comb[(size_t)i * 48 + 36 + lane];
  }
  __syncthreads();
  if (lane == 0){
    float mx = o6[0];
    for (int c = 1; c < 6; c++) mx = fmaxf(mx, o6[c]);
    float se = 0.f;
    for (int c = 0; c < 6; c++) se += __expf(o6[c] - mx);
    float lse = logf(se);
    for (int c = 0; c < 6; c++) out[(size_t)i * 6 + c] = o6[c] - mx - lse;
  }
}

// ---------------------------------------------------------------------------
extern "C" void kernel_launch(void* const* d_in, const int* in_sizes, int n_in,
                              void* d_out, int out_size, void* d_ws, size_t ws_size,
                              hipStream_t stream){
  const float* nf  = (const float*)d_in[0];
  const int*   ei  = (const int*)d_in[1];
  const float* W1  = (const float*)d_in[2];
  const float* as1 = (const float*)d_in[3];
  const float* ad1 = (const float*)d_in[4];
  const float* b1  = (const float*)d_in[5];
  const float* Wl1 = (const float*)d_in[6];
  const float* bl1 = (const float*)d_in[7];
  const float* W2  = (const float*)d_in[8];
  const float* as2 = (const float*)d_in[9];
  const float* ad2 = (const float*)d_in[10];
  const float* b2  = (const float*)d_in[11];
  const float* Wl2 = (const float*)d_in[12];
  const float* bl2 = (const float*)d_in[13];
  const float* W3  = (const float*)d_in[14];
  const float* as3 = (const float*)d_in[15];
  const float* ad3 = (const float*)d_in[16];
  const float* b3  = (const float*)d_in[17];
  const float* Wl3 = (const float*)d_in[18];
  const float* bl3 = (const float*)d_in[19];
  float* out = (float*)d_out;

  const int N = in_sizes[0] / 512;   // 10000
  const int E = in_sizes[1] / 2;     // 160000
  const int Mpad = ((N + 127) / 128) * 128;   // 10112
  const int Mtiles = Mpad / 128;              // 79
  const int Gm = (Mtiles + 7) / 8;            // 10

  char* ws = (char*)d_ws;
  size_t off = 0;
  auto alloc = [&](size_t bytes) -> char* {
    char* p = ws + off;
    off += (bytes + 255) & ~(size_t)255;
    return p;
  };
  unsigned short* Abf1 = (unsigned short*)alloc((size_t)Mpad * 512 * 2);
  unsigned short* Abf2 = (unsigned short*)alloc((size_t)Mpad * 1024 * 2);
  unsigned char*  Hq   = (unsigned char*)alloc((size_t)N * 1024);
  unsigned short* Ybf  = (unsigned short*)alloc((size_t)N * 1024 * 2);
  // contiguous zero region: deg + (als,ald) a/b pairs + als3/ald3 + comb
  size_t zbytes = (size_t)N * 4            // deg
                + 4 * (size_t)N * 4 * 4    // als_a, ald_a, als_b, ald_b
                + 2 * (size_t)N * 6 * 4    // als3, ald3 (atomic-accumulated)
                + (size_t)N * 48 * 4;      // comb (atomic-accumulated, split-K)
  char*  zbase  = alloc(zbytes);
  int*   deg    = (int*)zbase;
  float* als_a  = (float*)(zbase + (size_t)N * 4);
  float* ald_a  = als_a + (size_t)N * 4;
  float* als_b  = ald_a + (size_t)N * 4;
  float* ald_b  = als_b + (size_t)N * 4;
  float* als3   = ald_b + (size_t)N * 4;
  float* ald3   = als3 + (size_t)N * 6;
  float* comb   = ald3 + (size_t)N * 6;
  float* biasc  = (float*)alloc(48 * 4);
  int* rp       = (int*)alloc((size_t)(N + 1) * 4);
  int* cur      = (int*)alloc((size_t)N * 4);
  int* colx     = (int*)alloc((size_t)E * 4);
  unsigned short* Wc1 = (unsigned short*)alloc((size_t)2048 * 512 * 2);
  unsigned short* Wc2 = (unsigned short*)alloc((size_t)2048 * 1024 * 2);
  unsigned short* Bt3 = (unsigned short*)alloc((size_t)128 * 1024 * 2);

  hipMemsetAsync(zbase, 0, zbytes, stream);

  int prepBlocks = 512 + 512 + 1024 + 1024 + 512 + (Mpad >> 1) + (Mpad - N)
                 + (E + 255) / 256;
  k_prep<<<prepBlocks, 256, 0, stream>>>(W1, Wl1, W2, Wl2, W3, Wl3, bl3,
                                         nf, ei, Wc1, Wc2, Bt3, biasc,
                                         Abf1, Abf2, deg, Mpad, N, E);
  k_scan   <<<1, 1024, 0, stream>>>(deg, rp, cur, N);
  k_scatter<<<(E + 255) / 256, 256, 0, stream>>>(ei, cur, colx, E);

  int blocksL = 8 * Gm * 16;
  int blocks3 = 8 * Gm * 4;          // split-K x4

  // layer 1 (attn dots fused into GEMM epilogue -> als_a/ald_a)
  k_mfma_gemm<<<blocksL, 256, 0, stream>>>(Abf1, Wc1, bl1, Hq, Ybf, nullptr,
                                           as1, ad1, als_a, ald_a,
                                           N, 512, 2048, Mtiles, Gm, 0);
  k_agg<<<N, 256, 0, stream>>>(Hq, Ybf, Abf2, b1, als_a, ald_a, rp, colx);

  // layer 2 (dots -> als_b/ald_b, pre-zeroed; no mid-stream memset)
  k_mfma_gemm<<<blocksL, 256, 0, stream>>>(Abf2, Wc2, bl2, Hq, Ybf, nullptr,
                                           as2, ad2, als_b, ald_b,
                                           N, 1024, 2048, Mtiles, Gm, 0);
  k_agg<<<N, 256, 0, stream>>>(Hq, Ybf, Abf2, b2, als_b, ald_b, rp, colx);

  // layer 3 (split-K x4; partial comb/als3/ald3 via atomics, pre-zeroed)
  k_mfma_gemm<<<blocks3, 256, 0, stream>>>(Abf2, Bt3, biasc, nullptr, nullptr, comb,
                                           as3, ad3, als3, ald3,
                                           N, 1024, 48, Mtiles, Gm, 1);
  k_layer3<<<N, 64, 0, stream>>>(comb, als3, ald3, b3, rp, colx, out);
}